// Round 10
// baseline (819.464 us; speedup 1.0000x reference)
//
#include <hip/hip_runtime.h>

#define D_FEAT 64
#define BUK_SHIFT 9            // bucket = node >> 9 (512 nodes per bucket)
#define NPBUK 512
#define MAX_BUK 256            // supports n_nodes <= 131072
#define SRC_BITS 20
#define SRC_MASK 0xFFFFFu
#define CHUNK_E 8192           // edges per scatter block
#define MAX_BUK_RECS 16384     // mean ~10.2K recs/bucket; 64KB LDS

// ---------------- bucket counts via per-block LDS histograms ----------------
__global__ __launch_bounds__(256) void bucket_count_kernel(
    const int* __restrict__ ref_a, const int* __restrict__ ref_b,
    int* __restrict__ buk_cnt, int n_edges) {
    __shared__ int hist[MAX_BUK];
    hist[threadIdx.x] = 0;
    __syncthreads();
    int stride = gridDim.x * blockDim.x;
    for (int e = blockIdx.x * blockDim.x + threadIdx.x; e < n_edges; e += stride) {
        atomicAdd(&hist[ref_a[e] >> BUK_SHIFT], 1);
        atomicAdd(&hist[ref_b[e] >> BUK_SHIFT], 1);
    }
    __syncthreads();
    int c = hist[threadIdx.x];
    if (c) atomicAdd(&buk_cnt[threadIdx.x], c);
}

// ---------------- exclusive scan of 256 bucket counts (single wave) ---------
__global__ void bucket_scan_kernel(int* __restrict__ bs, int* __restrict__ cursor,
                                   int* __restrict__ row_start, int n_nodes) {
    int lane = threadIdx.x;  // blockDim = 64
    int carry = 0;
    for (int base = 0; base < MAX_BUK; base += 64) {
        int i = base + lane;
        int v = bs[i];
        int inc = v;
        #pragma unroll
        for (int d = 1; d < 64; d <<= 1) {
            int t = __shfl_up(inc, d);
            if (lane >= d) inc += t;
        }
        int excl = carry + inc - v;
        bs[i] = excl;
        cursor[i] = excl;
        carry += __shfl(inc, 63);
    }
    if (lane == 0) {
        bs[MAX_BUK] = carry;        // == 2 * n_edges
        row_start[n_nodes] = carry; // CSR sentinel
    }
}

// ---------------- block-local two-pass bucketed scatter ---------------------
// Proven round 9: fixes cross-XCD write amplification (100MB -> ~logical).
__global__ __launch_bounds__(256) void bucket_scatter_kernel(
    const int* __restrict__ ref_a, const int* __restrict__ ref_b,
    int* __restrict__ gcur, unsigned* __restrict__ recs, int n_edges) {
    __shared__ int cnt[MAX_BUK];
    __shared__ int base[MAX_BUK];
    __shared__ int cur[MAX_BUK];
    int tid = threadIdx.x;
    int e0 = blockIdx.x * CHUNK_E;
    int e1 = min(e0 + CHUNK_E, n_edges);

    cnt[tid] = 0;
    __syncthreads();
    for (int e = e0 + tid; e < e1; e += 256) {
        atomicAdd(&cnt[ref_a[e] >> BUK_SHIFT], 1);
        atomicAdd(&cnt[ref_b[e] >> BUK_SHIFT], 1);
    }
    __syncthreads();
    int c = cnt[tid];
    base[tid] = c ? atomicAdd(&gcur[tid], c) : 0;
    cur[tid] = 0;
    __syncthreads();
    for (int e = e0 + tid; e < e1; e += 256) {
        int a = ref_a[e];
        int b = ref_b[e];
        int ba = a >> BUK_SHIFT;
        int pa = base[ba] + atomicAdd(&cur[ba], 1);
        recs[pa] = ((unsigned)(a & (NPBUK - 1)) << SRC_BITS) | (unsigned)b;
        int bb = b >> BUK_SHIFT;
        int pb = base[bb] + atomicAdd(&cur[bb], 1);
        recs[pb] = ((unsigned)(b & (NPBUK - 1)) << SRC_BITS) | (unsigned)a;
    }
}

// ---------------- per-bucket counting sort -> node-ordered CSR --------------
__global__ __launch_bounds__(256) void bucket_sort_kernel(
    const int* __restrict__ bucket_start,
    unsigned* __restrict__ recs,
    int* __restrict__ row_start, int n_nodes) {
    __shared__ unsigned buf[MAX_BUK_RECS];  // 64 KB
    __shared__ int cnt[NPBUK];
    __shared__ int lcur[NPBUK];
    int buk = blockIdx.x;
    int tid = threadIdx.x;
    int s = bucket_start[buk];
    int n = bucket_start[buk + 1] - s;
    for (int i = tid; i < NPBUK; i += 256) cnt[i] = 0;
    __syncthreads();
    for (int i = tid; i < n; i += 256) {
        unsigned r = recs[s + i];
        buf[i] = r;
        atomicAdd(&cnt[r >> SRC_BITS], 1);
    }
    __syncthreads();
    if (tid < 64) {  // wave 0: scan 512 counts with carry, emit row_start
        int lane = tid;
        int carry = 0;
        for (int b2 = 0; b2 < NPBUK; b2 += 64) {
            int i = b2 + lane;
            int v = cnt[i];
            int inc = v;
            #pragma unroll
            for (int d = 1; d < 64; d <<= 1) {
                int t = __shfl_up(inc, d);
                if (lane >= d) inc += t;
            }
            int excl = carry + inc - v;
            lcur[i] = excl;
            int vg = (buk << BUK_SHIFT) + i;
            if (vg < n_nodes) row_start[vg] = s + excl;
            carry += __shfl(inc, 63);
        }
    }
    __syncthreads();
    for (int i = tid; i < n; i += 256) {
        unsigned r = buf[i];
        int p = atomicAdd(&lcur[r >> SRC_BITS], 1);
        recs[s + p] = r & SRC_MASK;  // sorted by dst; value = src node id
    }
}

// ---------------- gather: agg[v] = X[v] + sum_{u in N(v)} X[u] --------------
// Proven kernel (rounds 3/8/9), byte-identical.
__global__ __launch_bounds__(256) void gather_kernel(
    const float* __restrict__ X,
    const int* __restrict__ row_start,
    const int* __restrict__ adj,
    float* __restrict__ agg, int n_nodes) {
    int gwid = (blockIdx.x * blockDim.x + threadIdx.x) >> 6;
    int j = threadIdx.x & 63;
    if (gwid >= n_nodes) return;
    int v = gwid;
    float acc = X[v * D_FEAT + j];
    int k = row_start[v];
    int kend = row_start[v + 1];
    float a0 = 0.f, a1 = 0.f, a2 = 0.f, a3 = 0.f;
    for (; k + 8 <= kend; k += 8) {
        int u0 = adj[k + 0], u1 = adj[k + 1], u2 = adj[k + 2], u3 = adj[k + 3];
        int u4 = adj[k + 4], u5 = adj[k + 5], u6 = adj[k + 6], u7 = adj[k + 7];
        float r0 = X[u0 * D_FEAT + j], r1 = X[u1 * D_FEAT + j];
        float r2 = X[u2 * D_FEAT + j], r3 = X[u3 * D_FEAT + j];
        float r4 = X[u4 * D_FEAT + j], r5 = X[u5 * D_FEAT + j];
        float r6 = X[u6 * D_FEAT + j], r7 = X[u7 * D_FEAT + j];
        a0 += r0; a1 += r1; a2 += r2; a3 += r3;
        a0 += r4; a1 += r5; a2 += r6; a3 += r7;
    }
    for (; k < kend; ++k) acc += X[adj[k] * D_FEAT + j];
    agg[v * D_FEAT + j] = acc + (a0 + a1) + (a2 + a3);
}

// ---------------- 2-layer MLP v2: weights in REGISTERS, grid-stride --------
// Lane j holds Wh[k][j], Wo[k][j] for all k (64+64 VGPRs, fully-unrolled
// constant indices -> no scratch). No weight LDS, no __syncthreads at all:
// x/h LDS is wave-local (write then broadcast float4 reads, same-address
// across lanes -> conflict-free broadcast). Grid-stride amortizes the
// one-time register weight load over ~6 groups of 16 nodes per block.
// Fixes round-9 mlp: 6250 tiny blocks x (32KB LDS stage + 2 barriers),
// occupancy 10.6%.
__global__ __launch_bounds__(256, 3) void mlp_kernel(
    float* __restrict__ agg,   // in-place: also the output
    const float* __restrict__ Wh, const float* __restrict__ bh,
    const float* __restrict__ Wo, const float* __restrict__ bo,
    int n_nodes) {
    __shared__ __align__(16) float x_lds[4][4][D_FEAT];
    __shared__ __align__(16) float h_lds[4][4][D_FEAT];

    int tid = threadIdx.x;
    int w = tid >> 6;
    int j = tid & 63;

    float wh[D_FEAT], wo[D_FEAT];
    #pragma unroll
    for (int k = 0; k < D_FEAT; ++k) wh[k] = Wh[k * D_FEAT + j];
    #pragma unroll
    for (int k = 0; k < D_FEAT; ++k) wo[k] = Wo[k * D_FEAT + j];
    float bhj = bh[j];
    float boj = bo[j];

    int ngroups = (n_nodes + 15) >> 4;
    for (int g = blockIdx.x; g < ngroups; g += gridDim.x) {
        int vbase = g * 16 + w * 4;

        #pragma unroll
        for (int nb = 0; nb < 4; ++nb) {
            int v = vbase + nb;
            x_lds[w][nb][j] = (v < n_nodes) ? agg[v * D_FEAT + j] : 0.0f;
        }

        // ---- layer 1: h = relu(x @ Wh + bh) ----
        float a0 = bhj, a1 = bhj, a2 = bhj, a3 = bhj;
        {
            const float4* x0 = (const float4*)x_lds[w][0];
            const float4* x1 = (const float4*)x_lds[w][1];
            const float4* x2 = (const float4*)x_lds[w][2];
            const float4* x3 = (const float4*)x_lds[w][3];
            #pragma unroll
            for (int k4 = 0; k4 < 16; ++k4) {
                float4 p0 = x0[k4], p1 = x1[k4], p2 = x2[k4], p3 = x3[k4];
                float w0 = wh[k4 * 4 + 0], w1 = wh[k4 * 4 + 1];
                float w2 = wh[k4 * 4 + 2], w3 = wh[k4 * 4 + 3];
                a0 = fmaf(p0.x, w0, a0); a0 = fmaf(p0.y, w1, a0); a0 = fmaf(p0.z, w2, a0); a0 = fmaf(p0.w, w3, a0);
                a1 = fmaf(p1.x, w0, a1); a1 = fmaf(p1.y, w1, a1); a1 = fmaf(p1.z, w2, a1); a1 = fmaf(p1.w, w3, a1);
                a2 = fmaf(p2.x, w0, a2); a2 = fmaf(p2.y, w1, a2); a2 = fmaf(p2.z, w2, a2); a2 = fmaf(p2.w, w3, a2);
                a3 = fmaf(p3.x, w0, a3); a3 = fmaf(p3.y, w1, a3); a3 = fmaf(p3.z, w2, a3); a3 = fmaf(p3.w, w3, a3);
            }
        }
        h_lds[w][0][j] = fmaxf(a0, 0.0f);
        h_lds[w][1][j] = fmaxf(a1, 0.0f);
        h_lds[w][2][j] = fmaxf(a2, 0.0f);
        h_lds[w][3][j] = fmaxf(a3, 0.0f);

        // ---- layer 2: out = relu(h @ Wo + bo) ----
        float c0 = boj, c1 = boj, c2 = boj, c3 = boj;
        {
            const float4* x0 = (const float4*)h_lds[w][0];
            const float4* x1 = (const float4*)h_lds[w][1];
            const float4* x2 = (const float4*)h_lds[w][2];
            const float4* x3 = (const float4*)h_lds[w][3];
            #pragma unroll
            for (int k4 = 0; k4 < 16; ++k4) {
                float4 p0 = x0[k4], p1 = x1[k4], p2 = x2[k4], p3 = x3[k4];
                float w0 = wo[k4 * 4 + 0], w1 = wo[k4 * 4 + 1];
                float w2 = wo[k4 * 4 + 2], w3 = wo[k4 * 4 + 3];
                c0 = fmaf(p0.x, w0, c0); c0 = fmaf(p0.y, w1, c0); c0 = fmaf(p0.z, w2, c0); c0 = fmaf(p0.w, w3, c0);
                c1 = fmaf(p1.x, w0, c1); c1 = fmaf(p1.y, w1, c1); c1 = fmaf(p1.z, w2, c1); c1 = fmaf(p1.w, w3, c1);
                c2 = fmaf(p2.x, w0, c2); c2 = fmaf(p2.y, w1, c2); c2 = fmaf(p2.z, w2, c2); c2 = fmaf(p2.w, w3, c2);
                c3 = fmaf(p3.x, w0, c3); c3 = fmaf(p3.y, w1, c3); c3 = fmaf(p3.z, w2, c3); c3 = fmaf(p3.w, w3, c3);
            }
        }
        if (vbase + 0 < n_nodes) agg[(vbase + 0) * D_FEAT + j] = fmaxf(c0, 0.0f);
        if (vbase + 1 < n_nodes) agg[(vbase + 1) * D_FEAT + j] = fmaxf(c1, 0.0f);
        if (vbase + 2 < n_nodes) agg[(vbase + 2) * D_FEAT + j] = fmaxf(c2, 0.0f);
        if (vbase + 3 < n_nodes) agg[(vbase + 3) * D_FEAT + j] = fmaxf(c3, 0.0f);
    }
}

extern "C" void kernel_launch(void* const* d_in, const int* in_sizes, int n_in,
                              void* d_out, int out_size, void* d_ws, size_t ws_size,
                              hipStream_t stream) {
    const float* X     = (const float*)d_in[0];
    const int*   ref_a = (const int*)d_in[1];
    const int*   ref_b = (const int*)d_in[2];
    // d_in[3]=v_map, d_in[4]=v_count : unused by the reference
    const float* Wh    = (const float*)d_in[5];
    const float* bh    = (const float*)d_in[6];
    const float* Wo    = (const float*)d_in[7];
    const float* bo    = (const float*)d_in[8];
    float* out = (float*)d_out;

    int n_nodes = in_sizes[0] / D_FEAT;
    int n_edges = in_sizes[1];
    int nbuk = (n_nodes + NPBUK - 1) / NPBUK;   // 196 for 100K nodes

    // ws layout (ints): buk_cnt/bucket_start (MAX_BUK+1) | cursor (MAX_BUK)
    //                   | row_start (n_nodes+1) | recs (2*n_edges)  ~= 8.4 MB
    int* buk_cnt   = (int*)d_ws;             // becomes bucket_start after scan
    int* cursor    = buk_cnt + (MAX_BUK + 1);
    int* row_start = cursor + MAX_BUK;
    unsigned* recs = (unsigned*)(row_start + n_nodes + 1);

    hipMemsetAsync(buk_cnt, 0, (MAX_BUK + 1) * sizeof(int), stream);
    bucket_count_kernel<<<256, 256, 0, stream>>>(ref_a, ref_b, buk_cnt, n_edges);
    bucket_scan_kernel<<<1, 64, 0, stream>>>(buk_cnt, cursor, row_start, n_nodes);
    bucket_scatter_kernel<<<(n_edges + CHUNK_E - 1) / CHUNK_E, 256, 0, stream>>>(
        ref_a, ref_b, cursor, recs, n_edges);
    bucket_sort_kernel<<<nbuk, 256, 0, stream>>>(buk_cnt, recs, row_start, n_nodes);

    // gather into d_out (agg), then MLP in-place on d_out
    int gblocks = (n_nodes * 64 + 255) / 256;   // one wave per node
    gather_kernel<<<gblocks, 256, 0, stream>>>(X, row_start, (const int*)recs,
                                               out, n_nodes);

    mlp_kernel<<<1024, 256, 0, stream>>>(out, Wh, bh, Wo, bo, n_nodes);
}

// Round 11
// 329.175 us; speedup vs baseline: 2.4894x; 2.4894x over previous
//
#include <hip/hip_runtime.h>

#define D_FEAT 64
#define BUK_SHIFT 9            // bucket = node >> 9 (512 nodes per bucket)
#define NPBUK 512
#define MAX_BUK 256            // supports n_nodes <= 131072
#define SRC_BITS 20
#define SRC_MASK 0xFFFFFu
#define CHUNK_E 8192           // edges per scatter block
#define MAX_BUK_RECS 16384     // mean ~10.2K recs/bucket; 64KB LDS

// ---------------- bucket counts via per-block LDS histograms ----------------
__global__ __launch_bounds__(256) void bucket_count_kernel(
    const int* __restrict__ ref_a, const int* __restrict__ ref_b,
    int* __restrict__ buk_cnt, int n_edges) {
    __shared__ int hist[MAX_BUK];
    hist[threadIdx.x] = 0;
    __syncthreads();
    int stride = gridDim.x * blockDim.x;
    for (int e = blockIdx.x * blockDim.x + threadIdx.x; e < n_edges; e += stride) {
        atomicAdd(&hist[ref_a[e] >> BUK_SHIFT], 1);
        atomicAdd(&hist[ref_b[e] >> BUK_SHIFT], 1);
    }
    __syncthreads();
    int c = hist[threadIdx.x];
    if (c) atomicAdd(&buk_cnt[threadIdx.x], c);
}

// ---------------- exclusive scan of 256 bucket counts (single wave) ---------
__global__ void bucket_scan_kernel(int* __restrict__ bs, int* __restrict__ cursor,
                                   int* __restrict__ row_start, int n_nodes) {
    int lane = threadIdx.x;  // blockDim = 64
    int carry = 0;
    for (int base = 0; base < MAX_BUK; base += 64) {
        int i = base + lane;
        int v = bs[i];
        int inc = v;
        #pragma unroll
        for (int d = 1; d < 64; d <<= 1) {
            int t = __shfl_up(inc, d);
            if (lane >= d) inc += t;
        }
        int excl = carry + inc - v;
        bs[i] = excl;
        cursor[i] = excl;
        carry += __shfl(inc, 63);
    }
    if (lane == 0) {
        bs[MAX_BUK] = carry;        // == 2 * n_edges
        row_start[n_nodes] = carry; // CSR sentinel
    }
}

// ---------------- block-local two-pass bucketed scatter ---------------------
// Proven round 9: fixes cross-XCD write amplification (100MB -> ~logical).
__global__ __launch_bounds__(256) void bucket_scatter_kernel(
    const int* __restrict__ ref_a, const int* __restrict__ ref_b,
    int* __restrict__ gcur, unsigned* __restrict__ recs, int n_edges) {
    __shared__ int cnt[MAX_BUK];
    __shared__ int base[MAX_BUK];
    __shared__ int cur[MAX_BUK];
    int tid = threadIdx.x;
    int e0 = blockIdx.x * CHUNK_E;
    int e1 = min(e0 + CHUNK_E, n_edges);

    cnt[tid] = 0;
    __syncthreads();
    for (int e = e0 + tid; e < e1; e += 256) {
        atomicAdd(&cnt[ref_a[e] >> BUK_SHIFT], 1);
        atomicAdd(&cnt[ref_b[e] >> BUK_SHIFT], 1);
    }
    __syncthreads();
    int c = cnt[tid];
    base[tid] = c ? atomicAdd(&gcur[tid], c) : 0;
    cur[tid] = 0;
    __syncthreads();
    for (int e = e0 + tid; e < e1; e += 256) {
        int a = ref_a[e];
        int b = ref_b[e];
        int ba = a >> BUK_SHIFT;
        int pa = base[ba] + atomicAdd(&cur[ba], 1);
        recs[pa] = ((unsigned)(a & (NPBUK - 1)) << SRC_BITS) | (unsigned)b;
        int bb = b >> BUK_SHIFT;
        int pb = base[bb] + atomicAdd(&cur[bb], 1);
        recs[pb] = ((unsigned)(b & (NPBUK - 1)) << SRC_BITS) | (unsigned)a;
    }
}

// ---------------- per-bucket counting sort -> node-ordered CSR --------------
__global__ __launch_bounds__(256) void bucket_sort_kernel(
    const int* __restrict__ bucket_start,
    unsigned* __restrict__ recs,
    int* __restrict__ row_start, int n_nodes) {
    __shared__ unsigned buf[MAX_BUK_RECS];  // 64 KB
    __shared__ int cnt[NPBUK];
    __shared__ int lcur[NPBUK];
    int buk = blockIdx.x;
    int tid = threadIdx.x;
    int s = bucket_start[buk];
    int n = bucket_start[buk + 1] - s;
    for (int i = tid; i < NPBUK; i += 256) cnt[i] = 0;
    __syncthreads();
    for (int i = tid; i < n; i += 256) {
        unsigned r = recs[s + i];
        buf[i] = r;
        atomicAdd(&cnt[r >> SRC_BITS], 1);
    }
    __syncthreads();
    if (tid < 64) {  // wave 0: scan 512 counts with carry, emit row_start
        int lane = tid;
        int carry = 0;
        for (int b2 = 0; b2 < NPBUK; b2 += 64) {
            int i = b2 + lane;
            int v = cnt[i];
            int inc = v;
            #pragma unroll
            for (int d = 1; d < 64; d <<= 1) {
                int t = __shfl_up(inc, d);
                if (lane >= d) inc += t;
            }
            int excl = carry + inc - v;
            lcur[i] = excl;
            int vg = (buk << BUK_SHIFT) + i;
            if (vg < n_nodes) row_start[vg] = s + excl;
            carry += __shfl(inc, 63);
        }
    }
    __syncthreads();
    for (int i = tid; i < n; i += 256) {
        unsigned r = buf[i];
        int p = atomicAdd(&lcur[r >> SRC_BITS], 1);
        recs[s + p] = r & SRC_MASK;  // sorted by dst; value = src node id
    }
}

// ---------------- gather: agg[v] = X[v] + sum_{u in N(v)} X[u] --------------
// Proven kernel (rounds 3/8/9), byte-identical.
__global__ __launch_bounds__(256) void gather_kernel(
    const float* __restrict__ X,
    const int* __restrict__ row_start,
    const int* __restrict__ adj,
    float* __restrict__ agg, int n_nodes) {
    int gwid = (blockIdx.x * blockDim.x + threadIdx.x) >> 6;
    int j = threadIdx.x & 63;
    if (gwid >= n_nodes) return;
    int v = gwid;
    float acc = X[v * D_FEAT + j];
    int k = row_start[v];
    int kend = row_start[v + 1];
    float a0 = 0.f, a1 = 0.f, a2 = 0.f, a3 = 0.f;
    for (; k + 8 <= kend; k += 8) {
        int u0 = adj[k + 0], u1 = adj[k + 1], u2 = adj[k + 2], u3 = adj[k + 3];
        int u4 = adj[k + 4], u5 = adj[k + 5], u6 = adj[k + 6], u7 = adj[k + 7];
        float r0 = X[u0 * D_FEAT + j], r1 = X[u1 * D_FEAT + j];
        float r2 = X[u2 * D_FEAT + j], r3 = X[u3 * D_FEAT + j];
        float r4 = X[u4 * D_FEAT + j], r5 = X[u5 * D_FEAT + j];
        float r6 = X[u6 * D_FEAT + j], r7 = X[u7 * D_FEAT + j];
        a0 += r0; a1 += r1; a2 += r2; a3 += r3;
        a0 += r4; a1 += r5; a2 += r6; a3 += r7;
    }
    for (; k < kend; ++k) acc += X[adj[k] * D_FEAT + j];
    agg[v * D_FEAT + j] = acc + (a0 + a1) + (a2 + a3);
}

// ---------------- 2-layer MLP v3: LDS weights + grid-stride -----------------
// Round-9's proven LDS math engine (VGPR ~50, no spill — round-10's
// register-weight variant spilled to scratch: VGPR=84, 2.1 GB HBM thrash)
// + round-10's grid-stride structure (weights staged ONCE per block, ~6
// groups amortize it; no barriers inside the group loop: x/h LDS is
// wave-local write -> same-address broadcast read).
// LDS 40KB -> 4 blocks/CU = 16 waves/CU (~50%), vs round-9's 10.6%.
__global__ __launch_bounds__(256) void mlp_kernel(
    float* __restrict__ agg,   // in-place: also the output
    const float* __restrict__ Wh, const float* __restrict__ bh,
    const float* __restrict__ Wo, const float* __restrict__ bo,
    int n_nodes) {
    __shared__ __align__(16) float wh_lds[D_FEAT * D_FEAT];
    __shared__ __align__(16) float wo_lds[D_FEAT * D_FEAT];
    __shared__ __align__(16) float x_lds[4][4][D_FEAT];
    __shared__ __align__(16) float h_lds[4][4][D_FEAT];

    int tid = threadIdx.x;
    {
        const float4* Wh4 = (const float4*)Wh;
        const float4* Wo4 = (const float4*)Wo;
        float4* wh4 = (float4*)wh_lds;
        float4* wo4 = (float4*)wo_lds;
        for (int i = tid; i < D_FEAT * D_FEAT / 4; i += 256) {
            wh4[i] = Wh4[i];
            wo4[i] = Wo4[i];
        }
    }
    int w = tid >> 6;
    int j = tid & 63;
    float bhj = bh[j];
    float boj = bo[j];
    __syncthreads();   // weights staged once per block

    int ngroups = (n_nodes + 15) >> 4;
    for (int g = blockIdx.x; g < ngroups; g += gridDim.x) {
        int vbase = g * 16 + w * 4;

        #pragma unroll
        for (int nb = 0; nb < 4; ++nb) {
            int v = vbase + nb;
            x_lds[w][nb][j] = (v < n_nodes) ? agg[v * D_FEAT + j] : 0.0f;
        }

        // ---- layer 1: h = relu(x @ Wh + bh) ----
        float a0 = bhj, a1 = bhj, a2 = bhj, a3 = bhj;
        {
            const float4* x0 = (const float4*)x_lds[w][0];
            const float4* x1 = (const float4*)x_lds[w][1];
            const float4* x2 = (const float4*)x_lds[w][2];
            const float4* x3 = (const float4*)x_lds[w][3];
            #pragma unroll
            for (int k4 = 0; k4 < 16; ++k4) {
                float4 p0 = x0[k4], p1 = x1[k4], p2 = x2[k4], p3 = x3[k4];
                float w0 = wh_lds[(k4 * 4 + 0) * D_FEAT + j];
                float w1 = wh_lds[(k4 * 4 + 1) * D_FEAT + j];
                float w2 = wh_lds[(k4 * 4 + 2) * D_FEAT + j];
                float w3 = wh_lds[(k4 * 4 + 3) * D_FEAT + j];
                a0 = fmaf(p0.x, w0, a0); a0 = fmaf(p0.y, w1, a0); a0 = fmaf(p0.z, w2, a0); a0 = fmaf(p0.w, w3, a0);
                a1 = fmaf(p1.x, w0, a1); a1 = fmaf(p1.y, w1, a1); a1 = fmaf(p1.z, w2, a1); a1 = fmaf(p1.w, w3, a1);
                a2 = fmaf(p2.x, w0, a2); a2 = fmaf(p2.y, w1, a2); a2 = fmaf(p2.z, w2, a2); a2 = fmaf(p2.w, w3, a2);
                a3 = fmaf(p3.x, w0, a3); a3 = fmaf(p3.y, w1, a3); a3 = fmaf(p3.z, w2, a3); a3 = fmaf(p3.w, w3, a3);
            }
        }
        h_lds[w][0][j] = fmaxf(a0, 0.0f);
        h_lds[w][1][j] = fmaxf(a1, 0.0f);
        h_lds[w][2][j] = fmaxf(a2, 0.0f);
        h_lds[w][3][j] = fmaxf(a3, 0.0f);

        // ---- layer 2: out = relu(h @ Wo + bo) ----
        float c0 = boj, c1 = boj, c2 = boj, c3 = boj;
        {
            const float4* x0 = (const float4*)h_lds[w][0];
            const float4* x1 = (const float4*)h_lds[w][1];
            const float4* x2 = (const float4*)h_lds[w][2];
            const float4* x3 = (const float4*)h_lds[w][3];
            #pragma unroll
            for (int k4 = 0; k4 < 16; ++k4) {
                float4 p0 = x0[k4], p1 = x1[k4], p2 = x2[k4], p3 = x3[k4];
                float w0 = wo_lds[(k4 * 4 + 0) * D_FEAT + j];
                float w1 = wo_lds[(k4 * 4 + 1) * D_FEAT + j];
                float w2 = wo_lds[(k4 * 4 + 2) * D_FEAT + j];
                float w3 = wo_lds[(k4 * 4 + 3) * D_FEAT + j];
                c0 = fmaf(p0.x, w0, c0); c0 = fmaf(p0.y, w1, c0); c0 = fmaf(p0.z, w2, c0); c0 = fmaf(p0.w, w3, c0);
                c1 = fmaf(p1.x, w0, c1); c1 = fmaf(p1.y, w1, c1); c1 = fmaf(p1.z, w2, c1); c1 = fmaf(p1.w, w3, c1);
                c2 = fmaf(p2.x, w0, c2); c2 = fmaf(p2.y, w1, c2); c2 = fmaf(p2.z, w2, c2); c2 = fmaf(p2.w, w3, c2);
                c3 = fmaf(p3.x, w0, c3); c3 = fmaf(p3.y, w1, c3); c3 = fmaf(p3.z, w2, c3); c3 = fmaf(p3.w, w3, c3);
            }
        }
        if (vbase + 0 < n_nodes) agg[(vbase + 0) * D_FEAT + j] = fmaxf(c0, 0.0f);
        if (vbase + 1 < n_nodes) agg[(vbase + 1) * D_FEAT + j] = fmaxf(c1, 0.0f);
        if (vbase + 2 < n_nodes) agg[(vbase + 2) * D_FEAT + j] = fmaxf(c2, 0.0f);
        if (vbase + 3 < n_nodes) agg[(vbase + 3) * D_FEAT + j] = fmaxf(c3, 0.0f);
    }
}

extern "C" void kernel_launch(void* const* d_in, const int* in_sizes, int n_in,
                              void* d_out, int out_size, void* d_ws, size_t ws_size,
                              hipStream_t stream) {
    const float* X     = (const float*)d_in[0];
    const int*   ref_a = (const int*)d_in[1];
    const int*   ref_b = (const int*)d_in[2];
    // d_in[3]=v_map, d_in[4]=v_count : unused by the reference
    const float* Wh    = (const float*)d_in[5];
    const float* bh    = (const float*)d_in[6];
    const float* Wo    = (const float*)d_in[7];
    const float* bo    = (const float*)d_in[8];
    float* out = (float*)d_out;

    int n_nodes = in_sizes[0] / D_FEAT;
    int n_edges = in_sizes[1];
    int nbuk = (n_nodes + NPBUK - 1) / NPBUK;   // 196 for 100K nodes

    // ws layout (ints): buk_cnt/bucket_start (MAX_BUK+1) | cursor (MAX_BUK)
    //                   | row_start (n_nodes+1) | recs (2*n_edges)  ~= 8.4 MB
    int* buk_cnt   = (int*)d_ws;             // becomes bucket_start after scan
    int* cursor    = buk_cnt + (MAX_BUK + 1);
    int* row_start = cursor + MAX_BUK;
    unsigned* recs = (unsigned*)(row_start + n_nodes + 1);

    hipMemsetAsync(buk_cnt, 0, (MAX_BUK + 1) * sizeof(int), stream);
    bucket_count_kernel<<<256, 256, 0, stream>>>(ref_a, ref_b, buk_cnt, n_edges);
    bucket_scan_kernel<<<1, 64, 0, stream>>>(buk_cnt, cursor, row_start, n_nodes);
    bucket_scatter_kernel<<<(n_edges + CHUNK_E - 1) / CHUNK_E, 256, 0, stream>>>(
        ref_a, ref_b, cursor, recs, n_edges);
    bucket_sort_kernel<<<nbuk, 256, 0, stream>>>(buk_cnt, recs, row_start, n_nodes);

    // gather into d_out (agg), then MLP in-place on d_out
    int gblocks = (n_nodes * 64 + 255) / 256;   // one wave per node
    gather_kernel<<<gblocks, 256, 0, stream>>>(X, row_start, (const int*)recs,
                                               out, n_nodes);

    mlp_kernel<<<1024, 256, 0, stream>>>(out, Wh, bh, Wo, bo, n_nodes);
}